// Round 4
// baseline (70.342 us; speedup 1.0000x reference)
//
#include <hip/hip_runtime.h>

#define NB 8192
#define ND 128
#define NC 100
#define MARGIN_F 0.3f

#define NBLK 1024            // 4 blocks/CU
#define WAVES_PB 4           // 256 threads
// 1024 blocks * 4 waves * 2 rows = 8192 rows

// Single fused kernel: per-block partials + block-0 spin-reduce.
// Partials are published with LSB forced to 1 ("ready" flag); both 0xAAAAAAAA
// poison and 0x00000000 zeros have LSB 0, so detection is init-state-safe.
__global__ __launch_bounds__(256) void triplet_fused_kernel(
    const float* __restrict__ inputs,   // (NB, ND) fp32
    const int*   __restrict__ targets,  // (NB,) int32
    const int*   __restrict__ ixs,      // (NB, 2) int32
    const float* __restrict__ brdf,     // (NC, NC) fp32
    unsigned int* __restrict__ partial, // (NBLK,) published float bits | 1
    float*       __restrict__ out)      // scalar
{
    const int wave = threadIdx.x >> 6;
    const int lane = threadIdx.x & 63;
    const int sub  = lane >> 5;          // which of 2 rows in this wave
    const int sl   = lane & 31;          // slot within the row (32 lanes/row)
    const int wave_id = blockIdx.x * WAVES_PB + wave;   // 0..4095
    const int row = wave_id * 2 + sub;                  // 0..8191

    const int i0 = ixs[2 * row];
    const int i1 = ixs[2 * row + 1];

    // 32 lanes * 1 float4 = 128 floats = full row, coalesced dwordx4.
    const float4* xr = (const float4*)(inputs + (size_t)row * ND);
    const float4* xa = (const float4*)(inputs + (size_t)i0  * ND);
    const float4* xb = (const float4*)(inputs + (size_t)i1  * ND);

    float4 r = xr[sl];
    float4 a = xa[sl];
    float4 b = xb[sl];

    float da, db, t;
    t = r.x - a.x; da  = t * t;
    t = r.y - a.y; da += t * t;
    t = r.z - a.z; da += t * t;
    t = r.w - a.w; da += t * t;

    t = r.x - b.x; db  = t * t;
    t = r.y - b.y; db += t * t;
    t = r.z - b.z; db += t * t;
    t = r.w - b.w; db += t * t;

    // 5-step butterfly confined to each 32-lane group
    #pragma unroll
    for (int off = 1; off <= 16; off <<= 1) {
        da += __shfl_xor(da, off, 64);
        db += __shfl_xor(db, off, 64);
    }

    float acc = 0.0f;
    if (sl == 0) {   // lanes 0 and 32: finish their row
        float d0 = sqrtf(fmaxf(da, 1e-12f));
        float d1 = sqrtf(fmaxf(db, 1e-12f));
        int tt = targets[row];
        int t0 = targets[i0];
        int t1 = targets[i1];
        float md1 = brdf[tt * NC + t0];
        float md2 = brdf[tt * NC + t1];
        float diff = (md1 < md2) ? (d0 - d1) : (d1 - d0);
        acc = fmaxf(diff + MARGIN_F, 0.0f);
    }
    // sum lanes 0 and 32 into lane 0
    acc += __shfl_xor(acc, 32, 64);

    __shared__ float wsum[WAVES_PB];
    if (lane == 0) wsum[wave] = acc;
    __syncthreads();
    if (threadIdx.x == 0) {
        float s = wsum[0] + wsum[1] + wsum[2] + wsum[3];
        unsigned int bits = __float_as_uint(s) | 1u;   // ready flag, <=1 ulp error
        __hip_atomic_store(&partial[blockIdx.x], bits,
                           __ATOMIC_RELEASE, __HIP_MEMORY_SCOPE_AGENT);
    }

    // ---- block 0: wait for all partials and produce the final mean ----
    if (blockIdx.x != 0) return;

    float mysum = 0.0f;
    #pragma unroll
    for (int k = 0; k < NBLK / 256; ++k) {
        const int idx = threadIdx.x * (NBLK / 256) + k;
        unsigned int bits;
        for (;;) {
            bits = __hip_atomic_load(&partial[idx],
                                     __ATOMIC_ACQUIRE, __HIP_MEMORY_SCOPE_AGENT);
            if (bits & 1u) break;
            __builtin_amdgcn_s_sleep(1);
        }
        mysum += __uint_as_float(bits);
    }

    #pragma unroll
    for (int off = 1; off <= 32; off <<= 1)
        mysum += __shfl_xor(mysum, off, 64);

    __shared__ float fsum[WAVES_PB];
    if (lane == 0) fsum[wave] = mysum;
    __syncthreads();
    if (threadIdx.x == 0) {
        float total = fsum[0] + fsum[1] + fsum[2] + fsum[3];
        out[0] = total * (1.0f / (float)NB);
    }
}

extern "C" void kernel_launch(void* const* d_in, const int* in_sizes, int n_in,
                              void* d_out, int out_size, void* d_ws, size_t ws_size,
                              hipStream_t stream) {
    const float* inputs  = (const float*)d_in[0];
    const int*   targets = (const int*)d_in[1];
    const int*   ixs     = (const int*)d_in[2];
    const float* brdf    = (const float*)d_in[3];
    float* out = (float*)d_out;
    unsigned int* partial = (unsigned int*)d_ws;   // NBLK words of scratch

    triplet_fused_kernel<<<NBLK, 256, 0, stream>>>(inputs, targets, ixs, brdf, partial, out);
}

// Round 5
// 63.675 us; speedup vs baseline: 1.1047x; 1.1047x over previous
//
#include <hip/hip_runtime.h>

#define NB 8192
#define ND 128
#define NC 100
#define MARGIN_F 0.3f

#define NBLK1 1024           // stage-1 blocks: 4 per CU -> 4 waves/SIMD
#define WAVES_PB 4           // 256 threads
// 1024 blocks * 4 waves * 2 rows = 8192 rows

// Stage 1: 32 lanes per row, 2 rows per wave; block partial -> partial[blockIdx]
__global__ __launch_bounds__(256) void triplet_partial_kernel(
    const float* __restrict__ inputs,   // (NB, ND) fp32
    const int*   __restrict__ targets,  // (NB,) int32
    const int*   __restrict__ ixs,      // (NB, 2) int32
    const float* __restrict__ brdf,     // (NC, NC) fp32
    float*       __restrict__ partial)  // (NBLK1,)
{
    const int wave = threadIdx.x >> 6;
    const int lane = threadIdx.x & 63;
    const int sub  = lane >> 5;          // which of 2 rows in this wave
    const int sl   = lane & 31;          // slot within the row (32 lanes/row)
    const int wave_id = blockIdx.x * WAVES_PB + wave;   // 0..4095
    const int row = wave_id * 2 + sub;                  // 0..8191

    const int i0 = ixs[2 * row];
    const int i1 = ixs[2 * row + 1];

    // 32 lanes * float4 = 128 floats = full row, coalesced dwordx4.
    const float4* xr = (const float4*)(inputs + (size_t)row * ND);
    const float4* xa = (const float4*)(inputs + (size_t)i0  * ND);
    const float4* xb = (const float4*)(inputs + (size_t)i1  * ND);

    float4 r = xr[sl];
    float4 a = xa[sl];
    float4 b = xb[sl];

    float da, db, t;
    t = r.x - a.x; da  = t * t;
    t = r.y - a.y; da += t * t;
    t = r.z - a.z; da += t * t;
    t = r.w - a.w; da += t * t;

    t = r.x - b.x; db  = t * t;
    t = r.y - b.y; db += t * t;
    t = r.z - b.z; db += t * t;
    t = r.w - b.w; db += t * t;

    // 5-step butterfly confined to each 32-lane group
    #pragma unroll
    for (int off = 1; off <= 16; off <<= 1) {
        da += __shfl_xor(da, off, 64);
        db += __shfl_xor(db, off, 64);
    }

    float acc = 0.0f;
    if (sl == 0) {   // lanes 0 and 32: finish their row
        float d0 = sqrtf(fmaxf(da, 1e-12f));
        float d1 = sqrtf(fmaxf(db, 1e-12f));
        int tt = targets[row];
        int t0 = targets[i0];
        int t1 = targets[i1];
        float md1 = brdf[tt * NC + t0];
        float md2 = brdf[tt * NC + t1];
        float diff = (md1 < md2) ? (d0 - d1) : (d1 - d0);
        acc = fmaxf(diff + MARGIN_F, 0.0f);
    }
    acc += __shfl_xor(acc, 32, 64);   // lanes 0+32 -> lane 0

    __shared__ float wsum[WAVES_PB];
    if (lane == 0) wsum[wave] = acc;
    __syncthreads();
    if (threadIdx.x == 0)
        partial[blockIdx.x] = wsum[0] + wsum[1] + wsum[2] + wsum[3];
}

// Stage 2: one block reduces 1024 partials; overwrites out (no memset needed).
__global__ __launch_bounds__(256) void triplet_reduce_kernel(
    const float* __restrict__ partial,
    float*       __restrict__ out)
{
    const int wave = threadIdx.x >> 6;
    const int lane = threadIdx.x & 63;

    float4 v = ((const float4*)partial)[threadIdx.x];   // 256 * 4 = 1024
    float s = (v.x + v.y) + (v.z + v.w);

    #pragma unroll
    for (int off = 1; off <= 32; off <<= 1)
        s += __shfl_xor(s, off, 64);

    __shared__ float wsum[WAVES_PB];
    if (lane == 0) wsum[wave] = s;
    __syncthreads();
    if (threadIdx.x == 0)
        out[0] = (wsum[0] + wsum[1] + wsum[2] + wsum[3]) * (1.0f / (float)NB);
}

extern "C" void kernel_launch(void* const* d_in, const int* in_sizes, int n_in,
                              void* d_out, int out_size, void* d_ws, size_t ws_size,
                              hipStream_t stream) {
    const float* inputs  = (const float*)d_in[0];
    const int*   targets = (const int*)d_in[1];
    const int*   ixs     = (const int*)d_in[2];
    const float* brdf    = (const float*)d_in[3];
    float* out     = (float*)d_out;
    float* partial = (float*)d_ws;    // 1024 floats of scratch

    triplet_partial_kernel<<<NBLK1, 256, 0, stream>>>(inputs, targets, ixs, brdf, partial);
    triplet_reduce_kernel<<<1, 256, 0, stream>>>(partial, out);
}